// Round 5
// baseline (129.732 us; speedup 1.0000x reference)
//
#include <hip/hip_runtime.h>
#include <hip/hip_bf16.h>

#define LRELU_ALPHA 0.2f

typedef __attribute__((ext_vector_type(8))) short short8;
typedef __attribute__((ext_vector_type(4))) short short4v;
typedef __attribute__((ext_vector_type(4))) float f32x4;

__device__ __forceinline__ float bf2f(unsigned short u) {
  union { unsigned int i; float f; } x;
  x.i = ((unsigned int)u) << 16;
  return x.f;
}
__device__ __forceinline__ short f2bf(float f) {
  __hip_bfloat16 b = __float2bfloat16(f);
  union { __hip_bfloat16 b; short s; } u;
  u.b = b;
  return u.s;
}

// ---------------- K0a: Wt[f][t] = bf16(W[t][f]) ----------------
__global__ __launch_bounds__(256) void k0_wt(const float* __restrict__ W,
                                             __hip_bfloat16* __restrict__ Wt) {
  int t = blockIdx.x, f = threadIdx.x;
  Wt[f * 256 + t] = __float2bfloat16(W[t * 256 + f]);
}

// ---------------- K0b: Wa1[t] = sum_f W[t][f]*a1[f], Wa2 likewise ----------
__global__ __launch_bounds__(64) void k0_wa(const float* __restrict__ W,
                                            const float* __restrict__ a,
                                            float* __restrict__ Wa) {
  int t = blockIdx.x, lane = threadIdx.x;
  float4 wv = *reinterpret_cast<const float4*>(W + t * 256 + lane * 4);
  float4 a1 = *reinterpret_cast<const float4*>(a + lane * 4);
  float4 a2 = *reinterpret_cast<const float4*>(a + 256 + lane * 4);
  float p1 = wv.x * a1.x + wv.y * a1.y + wv.z * a1.z + wv.w * a1.w;
  float p2 = wv.x * a2.x + wv.y * a2.y + wv.z * a2.z + wv.w * a2.w;
  #pragma unroll
  for (int off = 32; off; off >>= 1) {
    p1 += __shfl_down(p1, off);
    p2 += __shfl_down(p2, off);
  }
  if (lane == 0) { Wa[t] = p1; Wa[256 + t] = p2; }
}

// ---------------- K0c: adj_norm (7x7) ----------------
__global__ __launch_bounds__(64) void k0_adj(const float* __restrict__ B,
                                             float* __restrict__ adjn) {
  int t = threadIdx.x;
  float v = 0.f;
  if (t < 49) v = B[t] + (((t / 7) == (t % 7)) ? 1.f : 0.f);
  float mn = (t < 49) ? v : 1e30f;
  float mx = (t < 49) ? v : -1e30f;
  #pragma unroll
  for (int off = 32; off; off >>= 1) {
    mn = fminf(mn, __shfl_xor(mn, off));
    mx = fmaxf(mx, __shfl_xor(mx, off));
  }
  float scaled = (v - mn) / (mx - mn);
  __shared__ float adj[49];
  __shared__ float dis[7];
  if (t < 49) adj[t] = scaled;
  __syncthreads();
  if (t < 7) {
    float s = 0.f;
    #pragma unroll
    for (int j = 0; j < 7; ++j) s += adj[t * 7 + j];
    dis[t] = 1.0f / sqrtf(s);
  }
  __syncthreads();
  if (t < 49) adjn[t] = adj[t] * dis[t / 7] * dis[t % 7];
}

// ---------------- K1s: s1/s2 streaming pass ----------------
// grid 1024: n = blk>>4, cs = blk&15 (16 c per block; wave handles 4 c's).
// Lane owns t = lane*4..lane*4+3 => 28 contiguous floats per c-row; v index
// is static in the unrolled code (no div/mod). Shfl-reduce over 64 lanes.
__global__ __launch_bounds__(256) void k1s(const float* __restrict__ h,
                                           const float* __restrict__ Wa,
                                           float* __restrict__ s1g,
                                           float* __restrict__ s2g) {
  const int blk = blockIdx.x;
  const int n = blk >> 4, cs = blk & 15;
  const int tid = threadIdx.x;
  const int lane = tid & 63, wave = tid >> 6;
  float wa1[4], wa2[4];
  #pragma unroll
  for (int q = 0; q < 4; ++q) {
    wa1[q] = Wa[lane * 4 + q];
    wa2[q] = Wa[256 + lane * 4 + q];
  }
  #pragma unroll
  for (int ci = 0; ci < 4; ++ci) {
    int c = cs * 16 + wave * 4 + ci;
    const float4* src =
        reinterpret_cast<const float4*>(h + (size_t)(n * 256 + c) * 1792 + lane * 28);
    float4 x[7];
    #pragma unroll
    for (int i = 0; i < 7; ++i) x[i] = src[i];
    const float* xf = reinterpret_cast<const float*>(x);
    float p1[7], p2[7];
    #pragma unroll
    for (int v = 0; v < 7; ++v) { p1[v] = 0.f; p2[v] = 0.f; }
    #pragma unroll
    for (int dt = 0; dt < 4; ++dt)
      #pragma unroll
      for (int v = 0; v < 7; ++v) {
        float val = xf[dt * 7 + v];
        p1[v] += val * wa1[dt];
        p2[v] += val * wa2[dt];
      }
    #pragma unroll
    for (int v = 0; v < 7; ++v) {
      #pragma unroll
      for (int off = 32; off; off >>= 1) {
        p1[v] += __shfl_xor(p1[v], off);
        p2[v] += __shfl_xor(p2[v], off);
      }
    }
    if (lane == 0) {
      #pragma unroll
      for (int v = 0; v < 7; ++v) {
        s1g[(n * 7 + v) * 256 + c] = p1[v];
        s2g[(n * 7 + v) * 256 + c] = p2[v];
      }
    }
  }
}

// ---------------- K1g: Wh = h^T @ W (bf16 MFMA), pure GEMM ----------------
// grid 2048: n = blk>>5, cb = blk&31 (8 c). M=56, K=256, F=256.
// Staging: thread owns (c = tid>>5, t-strip t0=(tid&31)*8): reads 2x 28
// contiguous floats, repacks per-v in regs, ds_write_b64 (no div, no scalar
// LDS scatter). k-loop: B-frags direct from global Wt (L2-hot), A from LDS,
// ZERO barriers inside. Store: repack D tiles into LDS (reusing As) then
// fully-coalesced dwordx4 global stores.
__global__ __launch_bounds__(256) void k1g(const float* __restrict__ h,
                                           const __hip_bfloat16* __restrict__ Wt,
                                           __hip_bfloat16* __restrict__ Wh) {
  __shared__ short As[56 * 264];  // 29568 B; reused as Wh repack buffer
  const int blk = blockIdx.x;
  const int n = blk >> 5, cb = blk & 31;
  const int tid = threadIdx.x;

  // ---- stage h -> As[(c*7+v)][t], vectorized, division-free
  {
    const int c8 = tid >> 5;            // 0..7
    const int t0 = (tid & 31) * 8;      // t strip base
    const float* src = h + (size_t)((n * 256 + cb * 8 + c8)) * 1792 + t0 * 7;
    #pragma unroll
    for (int th = 0; th < 2; ++th) {    // two 4-t halves
      float4 x[7];
      #pragma unroll
      for (int i = 0; i < 7; ++i)
        x[i] = reinterpret_cast<const float4*>(src + th * 28)[i];
      const float* xf = reinterpret_cast<const float*>(x);
      #pragma unroll
      for (int v = 0; v < 7; ++v) {
        short4v row;
        #pragma unroll
        for (int dt = 0; dt < 4; ++dt) row[dt] = f2bf(xf[dt * 7 + v]);
        *reinterpret_cast<short4v*>(As + (c8 * 7 + v) * 264 + t0 + th * 4) = row;
      }
    }
  }
  __syncthreads();

  const int lane = tid & 63, wave = tid >> 6;
  const int lr = lane & 15, lk = lane >> 4;
  const int f_base = wave * 64;

  f32x4 acc[4][4];
  #pragma unroll
  for (int mt = 0; mt < 4; ++mt)
    #pragma unroll
    for (int ft = 0; ft < 4; ++ft) acc[mt][ft] = (f32x4){0.f, 0.f, 0.f, 0.f};

  const short* WtS = reinterpret_cast<const short*>(Wt);

  int rowm[4];
  #pragma unroll
  for (int mt = 0; mt < 4; ++mt) {
    int m = mt * 16 + lr;
    rowm[mt] = (m < 56) ? m : 55;  // dup row; outputs >=56 never stored
  }

  #pragma unroll
  for (int kb = 0; kb < 8; ++kb) {
    short8 bfrag[4];
    #pragma unroll
    for (int ft = 0; ft < 4; ++ft)
      bfrag[ft] = *reinterpret_cast<const short8*>(
          WtS + (f_base + ft * 16 + lr) * 256 + kb * 32 + lk * 8);
    #pragma unroll
    for (int mt = 0; mt < 4; ++mt) {
      short8 afrag = *reinterpret_cast<const short8*>(
          As + rowm[mt] * 264 + kb * 32 + lk * 8);
      #pragma unroll
      for (int ft = 0; ft < 4; ++ft)
        acc[mt][ft] = __builtin_amdgcn_mfma_f32_16x16x32_bf16(afrag, bfrag[ft],
                                                              acc[mt][ft], 0, 0, 0);
    }
  }

  __syncthreads();  // all A reads done; reuse As as repack buffer

  // ---- repack D (bf16) into As[m][f] (row stride 264 to dodge conflicts)
  #pragma unroll
  for (int mt = 0; mt < 4; ++mt) {
    #pragma unroll
    for (int j = 0; j < 4; ++j) {
      int m = mt * 16 + lk * 4 + j;
      if (m < 56) {
        #pragma unroll
        for (int ft = 0; ft < 4; ++ft)
          As[m * 264 + f_base + ft * 16 + lr] = f2bf(acc[mt][ft][j]);
      }
    }
  }
  __syncthreads();

  // ---- coalesced store: 56 rows x 512 B contiguous block
  short* dst = reinterpret_cast<short*>(Wh) + (size_t)(n * 256 + cb * 8) * 1792;
  #pragma unroll
  for (int pass = 0; pass < 7; ++pass) {
    int r = pass * 8 + (tid >> 5);
    int col = tid & 31;
    short8 vrow = *reinterpret_cast<const short8*>(As + r * 264 + col * 8);
    *reinterpret_cast<short8*>(dst + r * 256 + col * 8) = vrow;
  }
}

// ---------------- K2: softmax over c -> att[n][c][i*7+j] ----------------
__global__ __launch_bounds__(256) void k2_soft(const float* __restrict__ s1g,
                                               const float* __restrict__ s2g,
                                               float* __restrict__ att) {
  __shared__ float s1L[1792], s2L[1792];
  const int n = blockIdx.x, tid = threadIdx.x;
  for (int idx = tid; idx < 1792; idx += 256) {
    s1L[idx] = s1g[n * 1792 + idx];
    s2L[idx] = s2g[n * 1792 + idx];
  }
  __syncthreads();
  const int lane = tid & 63, wave = tid >> 6;
  for (int p = wave; p < 49; p += 4) {
    int i = p / 7, j = p - i * 7;
    float ex[4];
    float mx = -1e30f;
    #pragma unroll
    for (int q = 0; q < 4; ++q) {
      int c = lane + q * 64;
      float e = s1L[i * 256 + c] + s2L[j * 256 + c];
      e = (e > 0.f) ? e : LRELU_ALPHA * e;
      ex[q] = e;
      mx = fmaxf(mx, e);
    }
    #pragma unroll
    for (int off = 32; off; off >>= 1) mx = fmaxf(mx, __shfl_xor(mx, off));
    float sm = 0.f;
    #pragma unroll
    for (int q = 0; q < 4; ++q) {
      ex[q] = __expf(ex[q] - mx);
      sm += ex[q];
    }
    #pragma unroll
    for (int off = 32; off; off >>= 1) sm += __shfl_xor(sm, off);
    float inv = 1.0f / sm;
    #pragma unroll
    for (int q = 0; q < 4; ++q) {
      int c = lane + q * 64;
      att[((size_t)n * 256 + c) * 49 + p] = ex[q] * inv;
    }
  }
}

// ---------------- K3: out[n,c,f,v] = elu( sum_j Wh[n,c,j,f] * M[j,v] ) ------
__global__ __launch_bounds__(256) void k3_out(const __hip_bfloat16* __restrict__ Wh,
                                              const float* __restrict__ att,
                                              const float* __restrict__ adjn,
                                              float* __restrict__ out) {
  __shared__ float attL[49], adjL[49], M[49];
  __shared__ float outL[1792];
  const int blk = blockIdx.x;
  const int n = blk >> 8, c = blk & 255;
  const int tid = threadIdx.x;
  if (tid < 49) {
    attL[tid] = att[((size_t)n * 256 + c) * 49 + tid];
    adjL[tid] = adjn[tid];
  }
  __syncthreads();
  if (tid < 49) {
    int j = tid / 7, v = tid - (tid / 7) * 7;
    float s = 0.f;
    #pragma unroll
    for (int i = 0; i < 7; ++i) s += attL[i * 7 + j] * adjL[i * 7 + v];
    M[tid] = s;
  }
  __syncthreads();
  const unsigned short* WhS = reinterpret_cast<const unsigned short*>(Wh) +
                              ((size_t)n * 256 + c) * 1792 + tid;
  float wh[7];
  #pragma unroll
  for (int j = 0; j < 7; ++j) wh[j] = bf2f(WhS[j * 256]);
  #pragma unroll
  for (int v = 0; v < 7; ++v) {
    float o = 0.f;
    #pragma unroll
    for (int j = 0; j < 7; ++j) o += wh[j] * M[j * 7 + v];
    o = (o > 0.f) ? o : (__expf(o) - 1.f);
    outL[tid * 7 + v] = o;
  }
  __syncthreads();
  float* dst = out + (size_t)(n * 256 + c) * 1792;
  for (int idx = tid; idx < 1792; idx += 256) dst[idx] = outL[idx];
}

extern "C" void kernel_launch(void* const* d_in, const int* in_sizes, int n_in,
                              void* d_out, int out_size, void* d_ws, size_t ws_size,
                              hipStream_t stream) {
  const float* h = (const float*)d_in[0];
  const float* W = (const float*)d_in[1];
  const float* a = (const float*)d_in[2];
  const float* B = (const float*)d_in[3];
  float* out = (float*)d_out;
  char* ws = (char*)d_ws;

  __hip_bfloat16* Wt = (__hip_bfloat16*)(ws + 0);        // 131072
  float* adjn = (float*)(ws + 131072);                   // 256
  float* Wa   = (float*)(ws + 131328);                   // 2048
  float* s1g  = (float*)(ws + 133376);                   // 458752
  float* s2g  = (float*)(ws + 592128);                   // 458752
  float* att  = (float*)(ws + 1050880);                  // 3211264
  __hip_bfloat16* Wh = (__hip_bfloat16*)(ws + 4262144);  // 58720256 (end 62982400)

  k0_wt<<<256, 256, 0, stream>>>(W, Wt);
  k0_wa<<<256, 64, 0, stream>>>(W, a, Wa);
  k0_adj<<<1, 64, 0, stream>>>(B, adjn);
  k1s<<<1024, 256, 0, stream>>>(h, Wa, s1g, s2g);
  k1g<<<2048, 256, 0, stream>>>(h, Wt, Wh);
  k2_soft<<<64, 256, 0, stream>>>(s1g, s2g, att);
  k3_out<<<16384, 256, 0, stream>>>(Wh, att, adjn, out);
}

// Round 6
// 124.375 us; speedup vs baseline: 1.0431x; 1.0431x over previous
//
#include <hip/hip_runtime.h>
#include <hip/hip_bf16.h>

#define LRELU_ALPHA 0.2f

typedef __attribute__((ext_vector_type(8))) short short8;
typedef __attribute__((ext_vector_type(4))) short short4v;
typedef __attribute__((ext_vector_type(4))) float f32x4;

__device__ __forceinline__ float bf2f(unsigned short u) {
  union { unsigned int i; float f; } x;
  x.i = ((unsigned int)u) << 16;
  return x.f;
}
__device__ __forceinline__ short f2bf(float f) {
  __hip_bfloat16 b = __float2bfloat16(f);
  union { __hip_bfloat16 b; short s; } u;
  u.b = b;
  return u.s;
}

// ---------------- K0a: Wt[f][t] = bf16(W[t][f]) ----------------
__global__ __launch_bounds__(256) void k0_wt(const float* __restrict__ W,
                                             __hip_bfloat16* __restrict__ Wt) {
  int t = blockIdx.x, f = threadIdx.x;
  Wt[f * 256 + t] = __float2bfloat16(W[t * 256 + f]);
}

// ---------------- K0b: Wa1[t] = sum_f W[t][f]*a1[f], Wa2 likewise ----------
__global__ __launch_bounds__(64) void k0_wa(const float* __restrict__ W,
                                            const float* __restrict__ a,
                                            float* __restrict__ Wa) {
  int t = blockIdx.x, lane = threadIdx.x;
  float4 wv = *reinterpret_cast<const float4*>(W + t * 256 + lane * 4);
  float4 a1 = *reinterpret_cast<const float4*>(a + lane * 4);
  float4 a2 = *reinterpret_cast<const float4*>(a + 256 + lane * 4);
  float p1 = wv.x * a1.x + wv.y * a1.y + wv.z * a1.z + wv.w * a1.w;
  float p2 = wv.x * a2.x + wv.y * a2.y + wv.z * a2.z + wv.w * a2.w;
  #pragma unroll
  for (int off = 32; off; off >>= 1) {
    p1 += __shfl_down(p1, off);
    p2 += __shfl_down(p2, off);
  }
  if (lane == 0) { Wa[t] = p1; Wa[256 + t] = p2; }
}

// ---------------- K0c: adj_norm (7x7) ----------------
__global__ __launch_bounds__(64) void k0_adj(const float* __restrict__ B,
                                             float* __restrict__ adjn) {
  int t = threadIdx.x;
  float v = 0.f;
  if (t < 49) v = B[t] + (((t / 7) == (t % 7)) ? 1.f : 0.f);
  float mn = (t < 49) ? v : 1e30f;
  float mx = (t < 49) ? v : -1e30f;
  #pragma unroll
  for (int off = 32; off; off >>= 1) {
    mn = fminf(mn, __shfl_xor(mn, off));
    mx = fmaxf(mx, __shfl_xor(mx, off));
  }
  float scaled = (v - mn) / (mx - mn);
  __shared__ float adj[49];
  __shared__ float dis[7];
  if (t < 49) adj[t] = scaled;
  __syncthreads();
  if (t < 7) {
    float s = 0.f;
    #pragma unroll
    for (int j = 0; j < 7; ++j) s += adj[t * 7 + j];
    dis[t] = 1.0f / sqrtf(s);
  }
  __syncthreads();
  if (t < 49) adjn[t] = adj[t] * dis[t / 7] * dis[t % 7];
}

// ---------------- K1s: s1/s2 streaming pass ----------------
// grid 1024: n = blk>>4, cs = blk&15 (16 c per block; wave handles 4 c's).
__global__ __launch_bounds__(256) void k1s(const float* __restrict__ h,
                                           const float* __restrict__ Wa,
                                           float* __restrict__ s1g,
                                           float* __restrict__ s2g) {
  const int blk = blockIdx.x;
  const int n = blk >> 4, cs = blk & 15;
  const int tid = threadIdx.x;
  const int lane = tid & 63, wave = tid >> 6;
  float wa1[4], wa2[4];
  #pragma unroll
  for (int q = 0; q < 4; ++q) {
    wa1[q] = Wa[lane * 4 + q];
    wa2[q] = Wa[256 + lane * 4 + q];
  }
  #pragma unroll
  for (int ci = 0; ci < 4; ++ci) {
    int c = cs * 16 + wave * 4 + ci;
    const float4* src =
        reinterpret_cast<const float4*>(h + (size_t)(n * 256 + c) * 1792 + lane * 28);
    float4 x[7];
    #pragma unroll
    for (int i = 0; i < 7; ++i) x[i] = src[i];
    const float* xf = reinterpret_cast<const float*>(x);
    float p1[7], p2[7];
    #pragma unroll
    for (int v = 0; v < 7; ++v) { p1[v] = 0.f; p2[v] = 0.f; }
    #pragma unroll
    for (int dt = 0; dt < 4; ++dt)
      #pragma unroll
      for (int v = 0; v < 7; ++v) {
        float val = xf[dt * 7 + v];
        p1[v] += val * wa1[dt];
        p2[v] += val * wa2[dt];
      }
    #pragma unroll
    for (int v = 0; v < 7; ++v) {
      #pragma unroll
      for (int off = 32; off; off >>= 1) {
        p1[v] += __shfl_xor(p1[v], off);
        p2[v] += __shfl_xor(p2[v], off);
      }
    }
    if (lane == 0) {
      #pragma unroll
      for (int v = 0; v < 7; ++v) {
        s1g[(n * 7 + v) * 256 + c] = p1[v];
        s2g[(n * 7 + v) * 256 + c] = p2[v];
      }
    }
  }
}

// ---------------- K2: softmax over c -> att[n][c][i*7+j] ----------------
__global__ __launch_bounds__(256) void k2_soft(const float* __restrict__ s1g,
                                               const float* __restrict__ s2g,
                                               float* __restrict__ att) {
  __shared__ float s1L[1792], s2L[1792];
  const int n = blockIdx.x, tid = threadIdx.x;
  for (int idx = tid; idx < 1792; idx += 256) {
    s1L[idx] = s1g[n * 1792 + idx];
    s2L[idx] = s2g[n * 1792 + idx];
  }
  __syncthreads();
  const int lane = tid & 63, wave = tid >> 6;
  for (int p = wave; p < 49; p += 4) {
    int i = p / 7, j = p - i * 7;
    float ex[4];
    float mx = -1e30f;
    #pragma unroll
    for (int q = 0; q < 4; ++q) {
      int c = lane + q * 64;
      float e = s1L[i * 256 + c] + s2L[j * 256 + c];
      e = (e > 0.f) ? e : LRELU_ALPHA * e;
      ex[q] = e;
      mx = fmaxf(mx, e);
    }
    #pragma unroll
    for (int off = 32; off; off >>= 1) mx = fmaxf(mx, __shfl_xor(mx, off));
    float sm = 0.f;
    #pragma unroll
    for (int q = 0; q < 4; ++q) {
      ex[q] = __expf(ex[q] - mx);
      sm += ex[q];
    }
    #pragma unroll
    for (int off = 32; off; off >>= 1) sm += __shfl_xor(sm, off);
    float inv = 1.0f / sm;
    #pragma unroll
    for (int q = 0; q < 4; ++q) {
      int c = lane + q * 64;
      att[((size_t)n * 256 + c) * 49 + p] = ex[q] * inv;
    }
  }
}

// ---------------- KC: fused GEMM + aggregation + ELU -> out ----------------
// grid 2048: n = blk>>5, cb = blk&31 (8 c). Per block:
//   1) stage h -> As[(c*7+v)][t] bf16 (div-free, ds_write_b64)
//   2) MFMA: D = A @ W  (B-frags direct from global Wt, zero in-loop barriers)
//   3) repack D into As[m][f] bf16
//   4) Ml[c][j][v] = sum_i att[n,c,i,j]*adjn[i,v]; out[c][f][v] =
//      elu(sum_j D[c*7+j][f] * Ml[c][j][v])  -- Wh never touches HBM.
__global__ __launch_bounds__(256) void kC(const float* __restrict__ h,
                                          const __hip_bfloat16* __restrict__ Wt,
                                          const float* __restrict__ att,
                                          const float* __restrict__ adjn,
                                          float* __restrict__ out) {
  __shared__ short As[56 * 264];   // 29568 B; h-tile, then D repack
  __shared__ float attL[392];      // 8 c x 49
  __shared__ float adjL[49];
  __shared__ float Ml[392];        // 8 c x (j*7+v)
  const int blk = blockIdx.x;
  const int n = blk >> 5, cb = blk & 31;
  const int tid = threadIdx.x;

  // ---- stage h -> As, division-free
  {
    const int c8 = tid >> 5;
    const int t0 = (tid & 31) * 8;
    const float* src = h + (size_t)((n * 256 + cb * 8 + c8)) * 1792 + t0 * 7;
    #pragma unroll
    for (int th = 0; th < 2; ++th) {
      float4 x[7];
      #pragma unroll
      for (int i = 0; i < 7; ++i)
        x[i] = reinterpret_cast<const float4*>(src + th * 28)[i];
      const float* xf = reinterpret_cast<const float*>(x);
      #pragma unroll
      for (int v = 0; v < 7; ++v) {
        short4v row;
        #pragma unroll
        for (int dt = 0; dt < 4; ++dt) row[dt] = f2bf(xf[dt * 7 + v]);
        *reinterpret_cast<short4v*>(As + (c8 * 7 + v) * 264 + t0 + th * 4) = row;
      }
    }
  }
  // also kick off att/adj loads (independent of As)
  for (int idx = tid; idx < 392; idx += 256)
    attL[idx] = att[(size_t)(n * 256 + cb * 8) * 49 + idx];
  if (tid < 49) adjL[tid] = adjn[tid];
  __syncthreads();

  const int lane = tid & 63, wave = tid >> 6;
  const int lr = lane & 15, lk = lane >> 4;
  const int f_base = wave * 64;

  f32x4 acc[4][4];
  #pragma unroll
  for (int mt = 0; mt < 4; ++mt)
    #pragma unroll
    for (int ft = 0; ft < 4; ++ft) acc[mt][ft] = (f32x4){0.f, 0.f, 0.f, 0.f};

  const short* WtS = reinterpret_cast<const short*>(Wt);

  int rowm[4];
  #pragma unroll
  for (int mt = 0; mt < 4; ++mt) {
    int m = mt * 16 + lr;
    rowm[mt] = (m < 56) ? m : 55;  // dup row; outputs >=56 never used
  }

  #pragma unroll
  for (int kb = 0; kb < 8; ++kb) {
    short8 bfrag[4];
    #pragma unroll
    for (int ft = 0; ft < 4; ++ft)
      bfrag[ft] = *reinterpret_cast<const short8*>(
          WtS + (f_base + ft * 16 + lr) * 256 + kb * 32 + lk * 8);
    #pragma unroll
    for (int mt = 0; mt < 4; ++mt) {
      short8 afrag = *reinterpret_cast<const short8*>(
          As + rowm[mt] * 264 + kb * 32 + lk * 8);
      #pragma unroll
      for (int ft = 0; ft < 4; ++ft)
        acc[mt][ft] = __builtin_amdgcn_mfma_f32_16x16x32_bf16(afrag, bfrag[ft],
                                                              acc[mt][ft], 0, 0, 0);
    }
  }

  // ---- compute Ml while MFMA results settle (uses attL/adjL only)
  for (int idx = tid; idx < 392; idx += 256) {
    int c = idx / 49;
    int r = idx - c * 49;
    int j = r / 7;
    int v = r - j * 7;
    float s = 0.f;
    #pragma unroll
    for (int i = 0; i < 7; ++i) s += attL[c * 49 + i * 7 + j] * adjL[i * 7 + v];
    Ml[idx] = s;
  }

  __syncthreads();  // all A reads done; reuse As for D repack

  // ---- repack D (bf16) into As[m][f]
  #pragma unroll
  for (int mt = 0; mt < 4; ++mt) {
    #pragma unroll
    for (int j = 0; j < 4; ++j) {
      int m = mt * 16 + lk * 4 + j;
      if (m < 56) {
        #pragma unroll
        for (int ft = 0; ft < 4; ++ft)
          As[m * 264 + f_base + ft * 16 + lr] = f2bf(acc[mt][ft][j]);
      }
    }
  }
  __syncthreads();

  // ---- per-c contraction: out[c][f][v] = elu(sum_j D[c*7+j][f]*Ml[c][j*7+v])
  const unsigned short* AsU = reinterpret_cast<const unsigned short*>(As);
  float* dst = out + (size_t)(n * 256 + cb * 8) * 1792 + tid * 7;
  #pragma unroll
  for (int c8 = 0; c8 < 8; ++c8) {
    float wh[7];
    #pragma unroll
    for (int j = 0; j < 7; ++j) wh[j] = bf2f(AsU[(c8 * 7 + j) * 264 + tid]);
    const float* Mc = Ml + c8 * 49;
    float* dc = dst + c8 * 1792;
    #pragma unroll
    for (int v = 0; v < 7; ++v) {
      float o = 0.f;
      #pragma unroll
      for (int j = 0; j < 7; ++j) o += wh[j] * Mc[j * 7 + v];
      o = (o > 0.f) ? o : (__expf(o) - 1.f);
      dc[v] = o;
    }
  }
}

extern "C" void kernel_launch(void* const* d_in, const int* in_sizes, int n_in,
                              void* d_out, int out_size, void* d_ws, size_t ws_size,
                              hipStream_t stream) {
  const float* h = (const float*)d_in[0];
  const float* W = (const float*)d_in[1];
  const float* a = (const float*)d_in[2];
  const float* B = (const float*)d_in[3];
  float* out = (float*)d_out;
  char* ws = (char*)d_ws;

  __hip_bfloat16* Wt = (__hip_bfloat16*)(ws + 0);  // 131072
  float* adjn = (float*)(ws + 131072);             // 256
  float* Wa   = (float*)(ws + 131328);             // 2048
  float* s1g  = (float*)(ws + 133376);             // 458752
  float* s2g  = (float*)(ws + 592128);             // 458752
  float* att  = (float*)(ws + 1050880);            // 3211264 (end 4262144)

  k0_wt<<<256, 256, 0, stream>>>(W, Wt);
  k0_wa<<<256, 64, 0, stream>>>(W, a, Wa);
  k0_adj<<<1, 64, 0, stream>>>(B, adjn);
  k1s<<<1024, 256, 0, stream>>>(h, Wa, s1g, s2g);
  k2_soft<<<64, 256, 0, stream>>>(s1g, s2g, att);
  kC<<<2048, 256, 0, stream>>>(h, Wt, att, adjn, out);
}